// Round 9
// baseline (223.991 us; speedup 1.0000x reference)
//
#include <hip/hip_runtime.h>
#include <math.h>

// Shapes (fixed): B=32, M=2, C=256, H=W=16, N=256, DIM=256, THR=0.1, RATIO=0.8
// out: fused (32,256,16,16) = 2,097,152 floats, then auto_enc_loss (1 float)
//
// R16 = R15 with ONE change: conv_dec moves to D=3 counted-vmcnt(6) pipeline
// at 72KB LDS, __launch_bounds__(256,2) -> 2 blocks/CU. (R9's D=3 was at
// 1 block/CU; R10 showed D=2 is occupancy-insensitive; this is the untested
// D=3 x 2-blocks/CU quadrant. Stage = 6 loads/thread -> vmcnt(6), not 4.)
// enc/recgemm/score/fuse unchanged from R15. 6 launches.

typedef __attribute__((ext_vector_type(8))) short short8;
typedef __attribute__((ext_vector_type(4))) float f32x4;

__device__ __forceinline__ void gload_lds16(const void* g, void* l) {
  __builtin_amdgcn_global_load_lds(
      (const __attribute__((address_space(1))) void*)g,
      (__attribute__((address_space(3))) void*)l, 16, 0, 0);
}

__device__ __forceinline__ unsigned short f2bf(float f) {
  unsigned u = __float_as_uint(f);
  unsigned r = (u + 0x7FFFu + ((u >> 16) & 1u)) >> 16;  // RNE
  return (unsigned short)r;
}

__device__ __forceinline__ unsigned mapf(float f) {
  unsigned u = __float_as_uint(f);
  return (u & 0x80000000u) ? ~u : (u | 0x80000000u);   // monotone float->uint
}
__device__ __forceinline__ float unmapf(unsigned u) {
  unsigned v = (u & 0x80000000u) ? (u & 0x7fffffffu) : ~u;
  return __uint_as_float(v);
}

// ---------------- merged prep: pack | weight-repack | halo-zero | slots | init
__global__ __launch_bounds__(256) void prep_k(
    const float* __restrict__ cf, const float* __restrict__ we,
    const float* __restrict__ wd, const float* __restrict__ fv,
    unsigned short* __restrict__ Xp, unsigned short* __restrict__ WrE,
    unsigned short* __restrict__ WrD, int* __restrict__ smr,
    float* __restrict__ vd, float4* __restrict__ sraw4,
    float* __restrict__ lacc, unsigned* __restrict__ mm) {
  const int bx = blockIdx.x, t = threadIdx.x;
  if (bx < 2048) {                       // pack: cf NCHW f32 -> padded NHWC bf16
    int xcdP = bx >> 8, r = bx & 255;    // XCD-grouped (matches enc img map)
    int img = xcdP * 8 + (r >> 5), ch = r & 31;
    int p = t;
    int ic0 = ch * 8;
    const float* sp = cf + (size_t)img * 65536 + (size_t)ic0 * 256 + p;
    unsigned short h[8];
#pragma unroll
    for (int i = 0; i < 8; ++i) h[i] = f2bf(sp[i * 256]);
    int y = p >> 4, x = p & 15;
    uint4 u;
    u.x = h[0] | (h[1] << 16); u.y = h[2] | (h[3] << 16);
    u.z = h[4] | (h[5] << 16); u.w = h[6] | (h[7] << 16);
    *(uint4*)&Xp[(size_t)img * 82944 + (size_t)(y * 18 + x + 19) * 256 + ic0] = u;
  } else if (bx < 2624) {                // wrk: OIHW f32 -> Wr[oc][s][ic] bf16
    int idx = (bx - 2048) * 256 + t;
    int ch = idx & 31, rest = idx >> 5;
    int s = rest % 9, ocx = rest / 9;
    int oc = ocx & 255, cv = ocx >> 8;
    const float* w = cv ? wd : we;
    unsigned short* o = cv ? WrD : WrE;
    int ic0 = ch * 8;
    unsigned short h[8];
#pragma unroll
    for (int i = 0; i < 8; ++i) h[i] = f2bf(w[(size_t)oc * 2304 + (ic0 + i) * 9 + s]);
    uint4 u;
    u.x = h[0] | (h[1] << 16); u.y = h[2] | (h[3] << 16);
    u.z = h[4] | (h[5] << 16); u.w = h[6] | (h[7] << 16);
    *(uint4*)&o[(size_t)oc * 2304 + s * 256 + ic0] = u;
  } else if (bx < 2752) {                // halo zero: Xp imgs 0..63, Midp 64..127
    int img = bx - 2624;
    uint4* base = (uint4*)Xp + (size_t)img * 10368;
    uint4 z; z.x = z.y = z.z = z.w = 0;
    for (int it = t; it < 2176; it += 256) {
      int px = it >> 5, c = it & 31;
      int y, x;
      if (px < 18)      { y = 0;  x = px; }
      else if (px < 36) { y = 17; x = px - 18; }
      else if (px < 52) { y = px - 35; x = 0; }
      else              { y = px - 51; x = 17; }
      base[(y * 18 + x) * 32 + c] = z;
    }
  } else if (bx < 2784) {                // slots: rank budget + dest maps
    const int b = bx - 2752;
    const float v0 = fv[(size_t)b * 512 + t];
    const float v1 = fv[(size_t)b * 512 + 256 + t];
    const unsigned long long bal0 = __ballot(v0 > 0.1f);
    const unsigned long long bal1 = __ballot(v1 > 0.1f);
    __shared__ int cnt0[4], cnt1[4], fc[2];
    const int wid = t >> 6, lane = t & 63;
    if (lane == 0) { cnt0[wid] = __popcll(bal0); cnt1[wid] = __popcll(bal1); }
    smr[b * 256 + t] = -1;
    vd[b * 256 + t] = 0.f;
    __syncthreads();
    if (t == 0) {
      int c0 = cnt0[0] + cnt0[1] + cnt0[2] + cnt0[3];
      int c1 = cnt1[0] + cnt1[1] + cnt1[2] + cnt1[3];
      int total = c0 + c1;
      int f0, f1;
      if (total > 256) {
        int a0 = (int)rintf(256.0f * (float)c0 / (float)total);
        f0 = a0; f1 = 256 - a0;
      } else { f0 = c0; f1 = c1; }
      fc[0] = max(f0, 0); fc[1] = max(f1, 0);
    }
    __syncthreads();
    const int c0 = fc[0], c1 = fc[1];
    if (t < c0) { smr[b * 256 + t] = t; vd[b * 256 + t] = v0; }
    if (t < c1) {
      int d = c0 + t;
      if (d < 256) { smr[b * 256 + d] = 256 + t; vd[b * 256 + d] = v1; }
    }
  } else {                               // zero sraw (24 blocks) + init (1)
    int z = bx - 2784;
    if (z < 24) {
      float4 zz; zz.x = zz.y = zz.z = zz.w = 0.f;
      sraw4[z * 256 + t] = zz;
    } else if (t == 0) {
      lacc[0] = 0.f; mm[0] = 0xFFFFFFFFu; mm[1] = 0u;
    }
  }
}

// ---------------- merged: ansb [0,1024) | bmt 1-jg-per-block [1024,2048) | Recp halo [2048,2080)
__global__ __launch_bounds__(256) void ansbmt_k(
    const float* __restrict__ fs, const float* __restrict__ fd,
    const int* __restrict__ smr, const float* __restrict__ vd,
    unsigned short* __restrict__ Ans, unsigned short* __restrict__ BmT,
    unsigned short* __restrict__ Recp) {
  const int bx = blockIdx.x, t = threadIdx.x;
  if (bx < 1024) {                       // Ans[b][c][j] = ns[c][j]*v_j
    int idx = bx * 256 + t;
    int ch = idx & 31, c = (idx >> 5) & 255, b = idx >> 13;
    int j0 = ch * 8;
    int si = smr[b * 256 + c];
    unsigned short h[8] = {0, 0, 0, 0, 0, 0, 0, 0};
    if (si >= 0) {
      int m = si >> 8, r = si & 255;
      const float* fp = fs + (((size_t)b * 2 + m) * 256 + r) * 256 + j0;
      const float* vp = vd + b * 256 + j0;
#pragma unroll
      for (int i = 0; i < 8; ++i) h[i] = f2bf(fp[i] * vp[i]);
    }
    uint4 u;
    u.x = h[0] | (h[1] << 16); u.y = h[2] | (h[3] << 16);
    u.z = h[4] | (h[5] << 16); u.w = h[6] | (h[7] << 16);
    *(uint4*)&Ans[(size_t)b * 65536 + c * 256 + j0] = u;
  } else if (bx < 2048) {                // BmT[b][p][jg*8..+8] = fd[b,m_p,jg*8+i,r_p]
    __shared__ float sIn[4096];          // 8 j x 2 m x 256 r
    const int q0 = bx - 1024;
    const int b = q0 >> 5, jg = q0 & 31;  // 32 b x 32 jg, fully parallel
    const int sp = smr[b * 256 + t];
    const int m_p = sp >> 8, r_p = sp & 255;
#pragma unroll
    for (int u = 0; u < 4; ++u) {
      int q = t * 4 + u;
      int rr = q >> 6, w = q & 63;
      int m = rr >> 3, i = rr & 7;
      float4 f = ((const float4*)fd)[((size_t)(b * 2 + m) * 256 + jg * 8 + i) * 64 + w];
      *(float4*)&sIn[i * 512 + m * 256 + w * 4] = f;
    }
    __syncthreads();
    unsigned short h[8] = {0, 0, 0, 0, 0, 0, 0, 0};
    if (sp >= 0) {
#pragma unroll
      for (int i = 0; i < 8; ++i) h[i] = f2bf(sIn[i * 512 + m_p * 256 + r_p]);
    }
    uint4 u;
    u.x = h[0] | (h[1] << 16); u.y = h[2] | (h[3] << 16);
    u.z = h[4] | (h[5] << 16); u.w = h[6] | (h[7] << 16);
    *(uint4*)&BmT[(size_t)b * 65536 + t * 256 + jg * 8] = u;
  } else {                               // Recp halo zero (32 imgs)
    int img = bx - 2048;
    uint4* base = (uint4*)Recp + (size_t)img * 10368;
    uint4 z; z.x = z.y = z.z = z.w = 0;
    for (int it = t; it < 2176; it += 256) {
      int px = it >> 5, c = it & 31;
      int y, x;
      if (px < 18)      { y = 0;  x = px; }
      else if (px < 36) { y = 17; x = px - 18; }
      else if (px < 52) { y = px - 35; x = 0; }
      else              { y = px - 51; x = 17; }
      base[(y * 18 + x) * 32 + c] = z;
    }
  }
}

// ---------------- merged conv_enc [0,512) + recgemm [512,1024) + score-cf [1024,1536)
__global__ __launch_bounds__(256, 3) void encrec_k(
    const unsigned short* __restrict__ Xin, const unsigned short* __restrict__ Wr,
    const float* __restrict__ bias,          unsigned short* __restrict__ outp,
    const unsigned short* __restrict__ BmT,  const unsigned short* __restrict__ Ans,
    unsigned short* __restrict__ Recp,       const float* __restrict__ cf,
    const float* __restrict__ wval,          float* __restrict__ sraw) {
  __shared__ __align__(16) char SS[49152];
  const int t = threadIdx.x, lane = t & 63, wave = t >> 6;
  const int L = blockIdx.x;

  if (L < 512) {  // ================= enc =================
    char (*S)[24576] = (char(*)[24576])SS;
    const int xcd = L & 7, sl = L >> 3;          // sl 0..63
    const int img = xcd * 8 + (sl & 7);
    const int tile = sl >> 3;                    // 0..7
    const int pt = tile & 3, ot = tile >> 2;

    int laneA[2], laneB[4];
#pragma unroll
    for (int r = 0; r < 2; ++r) {
      int id = r * 256 + t;
      int row = id >> 3, sub = id & 7, q = sub ^ (row & 7);
      int p = pt * 64 + row, y = p >> 4, x = p & 15;
      laneA[r] = (y * 18 + x) * 512 + q * 16;
    }
#pragma unroll
    for (int r = 0; r < 4; ++r) {
      int id = r * 256 + t;
      int row = id >> 3, sub = id & 7, q = sub ^ (row & 7);
      laneB[r] = (ot * 128 + row) * 4608 + q * 16;
    }
    const char* Ag = (const char*)Xin + (size_t)img * 165888;
    const char* Bg = (const char*)Wr;

    const int mlane = lane & 15, quad = lane >> 4;
    const int mw = wave >> 1, nw = wave & 1;
    int aoff[2][2], boff[4][2];
#pragma unroll
    for (int ks = 0; ks < 2; ++ks) {
#pragma unroll
      for (int i = 0; i < 2; ++i) {
        int rowm = mw * 32 + i * 16 + mlane;
        aoff[i][ks] = rowm * 128 + (((ks * 4 + quad) ^ (rowm & 7)) * 16);
      }
#pragma unroll
      for (int n = 0; n < 4; ++n) {
        int rown = nw * 64 + n * 16 + mlane;
        boff[n][ks] = 8192 + rown * 128 + (((ks * 4 + quad) ^ (rown & 7)) * 16);
      }
    }

    auto stage = [&](int kit, int buf) {         // 6 loads/thread
      int s = kit >> 2;
      int dy = s / 3, dx = s - dy * 3;
      int aG = (dy * 18 + dx) * 512 + (kit & 3) * 128;
      int bG = kit * 128;
      char* dst = S[buf];
#pragma unroll
      for (int r = 0; r < 2; ++r)
        gload_lds16(Ag + laneA[r] + aG, dst + r * 4096 + wave * 1024);
#pragma unroll
      for (int r = 0; r < 4; ++r)
        gload_lds16(Bg + laneB[r] + bG, dst + 8192 + r * 4096 + wave * 1024);
    };

    f32x4 acc[2][4] = {};
    auto compute = [&](int buf) {
      const char* Sb = S[buf];
#pragma unroll
      for (int ks = 0; ks < 2; ++ks) {
        short8 af[2], bf[4];
#pragma unroll
        for (int i = 0; i < 2; ++i) af[i] = *(const short8*)(Sb + aoff[i][ks]);
#pragma unroll
        for (int n = 0; n < 4; ++n) bf[n] = *(const short8*)(Sb + boff[n][ks]);
#pragma unroll
        for (int i = 0; i < 2; ++i)
#pragma unroll
          for (int n = 0; n < 4; ++n)
            acc[i][n] = __builtin_amdgcn_mfma_f32_16x16x32_bf16(af[i], bf[n], acc[i][n], 0, 0, 0);
      }
    };

    stage(0, 0);
    for (int kit = 0; kit < 36; ++kit) {
      int cur = kit & 1;
      asm volatile("s_waitcnt vmcnt(0)" ::: "memory");
      asm volatile("s_barrier" ::: "memory");
      if (kit + 1 < 36) stage(kit + 1, 1 - cur);
      compute(cur);
    }

#pragma unroll
    for (int i = 0; i < 2; ++i) {
      int m0 = pt * 64 + mw * 32 + i * 16 + quad * 4;
#pragma unroll
      for (int n = 0; n < 4; ++n) {
        int oc = ot * 128 + nw * 64 + n * 16 + mlane;
        float bv = bias[oc];
#pragma unroll
        for (int r = 0; r < 4; ++r) {
          int p = m0 + r;
          int y = p >> 4, x = p & 15;
          float v = fmaxf(acc[i][n][r] + bv, 0.f);
          outp[(size_t)img * 82944 + (size_t)(y * 18 + x + 19) * 256 + oc] = f2bf(v);
        }
      }
    }
  } else if (L < 1024) {  // ================= recgemm =================
    unsigned short (*S)[8192] = (unsigned short(*)[8192])SS;
    const int L2 = L - 512;
    const int b = L2 >> 4, tile = L2 & 15;
    const int pt = tile >> 2, ct = tile & 3;

    int laneA[2], laneB[2];
#pragma unroll
    for (int j = 0; j < 2; ++j) {
      int id = (wave * 2 + j) * 64 + lane;
      int row = id >> 3, q = (id & 7) ^ (row & 7);
      laneA[j] = (pt * 64 + row) * 512 + q * 16;
      laneB[j] = (ct * 64 + row) * 512 + q * 16;
    }
    const char* Ag = (const char*)BmT + (size_t)b * 131072;
    const char* Bg = (const char*)Ans + (size_t)b * 131072;

    const int mlane = lane & 15, quad = lane >> 4;
    const int mw = wave >> 1, nw = wave & 1;
    int aoff[2][2], boff[2][2];
#pragma unroll
    for (int ks = 0; ks < 2; ++ks) {
#pragma unroll
      for (int i = 0; i < 2; ++i) {
        int rowm = mw * 32 + i * 16 + mlane;
        aoff[i][ks] = rowm * 128 + (((ks * 4 + quad) ^ (rowm & 7)) * 16);
        int rown = nw * 32 + i * 16 + mlane;
        boff[i][ks] = 8192 + rown * 128 + (((ks * 4 + quad) ^ (rown & 7)) * 16);
      }
    }

    auto stage = [&](int kit, int buf) {
      int g = kit * 128;
      char* dst = (char*)S[buf];
#pragma unroll
      for (int j = 0; j < 2; ++j)
        gload_lds16(Ag + laneA[j] + g, dst + (wave * 2 + j) * 1024);
#pragma unroll
      for (int j = 0; j < 2; ++j)
        gload_lds16(Bg + laneB[j] + g, dst + 8192 + (wave * 2 + j) * 1024);
    };

    f32x4 acc[2][2] = {};
    auto compute = [&](int buf) {
      const char* Sb = (const char*)S[buf];
#pragma unroll
      for (int ks = 0; ks < 2; ++ks) {
        short8 af[2], bf[2];
#pragma unroll
        for (int i = 0; i < 2; ++i) {
          af[i] = *(const short8*)(Sb + aoff[i][ks]);
          bf[i] = *(const short8*)(Sb + boff[i][ks]);
        }
#pragma unroll
        for (int i = 0; i < 2; ++i)
#pragma unroll
          for (int n = 0; n < 2; ++n)
            acc[i][n] = __builtin_amdgcn_mfma_f32_16x16x32_bf16(af[i], bf[n], acc[i][n], 0, 0, 0);
      }
    };

    stage(0, 0);
    stage(1, 1);
    for (int kit = 0; kit < 3; ++kit) {
      asm volatile("s_waitcnt vmcnt(4)" ::: "memory");
      asm volatile("s_barrier" ::: "memory");
      int nb = kit + 2;
      if (nb < 4) stage(nb, nb % 3);
      compute(kit % 3);
    }
    asm volatile("s_waitcnt vmcnt(0)" ::: "memory");
    asm volatile("s_barrier" ::: "memory");
    compute(3 % 3);

#pragma unroll
    for (int i = 0; i < 2; ++i) {
      int m0 = pt * 64 + mw * 32 + i * 16 + quad * 4;
#pragma unroll
      for (int n = 0; n < 2; ++n) {
        int cc = ct * 64 + nw * 32 + n * 16 + mlane;
#pragma unroll
        for (int r = 0; r < 4; ++r) {
          int p = m0 + r;
          int y = p >> 4, x = p & 15;
          Recp[(size_t)b * 82944 + (size_t)(y * 18 + x + 19) * 256 + cc] = f2bf(acc[i][n][r]);
        }
      }
    }
  } else {  // ============ score phases 1,2 (cf-only, no dec dependency) ============
    const int u = L - 1024;              // 0..511
    const int b = u & 31, phase = 1 + ((u >> 5) & 1), icc = u >> 6;
    const int row = t >> 4, col = t & 15;
    float* s_in = (float*)SS;            // 11520 B
    float* s_wv = (float*)(SS + 11776);  // 288 B
    for (int i = t; i < 8 * 360; i += 256) s_in[i] = 0.f;
    const float* srcf = cf + ((size_t)b * 2 + (phase - 1)) * 65536;
    const int wofs = 2304;
    float acc = 0.f;
    for (int ic0 = icc * 32; ic0 < icc * 32 + 32; ic0 += 8) {
      __syncthreads();
#pragma unroll
      for (int i = 0; i < 8; ++i)
        s_in[i * 360 + (row + 1) * 20 + (col + 1)] = srcf[(ic0 + i) * 256 + t];
      if (t < 72) s_wv[t] = wval[wofs + ic0 * 9 + t];
      __syncthreads();
#pragma unroll
      for (int i = 0; i < 8; ++i)
#pragma unroll
        for (int ky = 0; ky < 3; ++ky)
#pragma unroll
          for (int kx = 0; kx < 3; ++kx)
            acc += s_in[i * 360 + (row + ky) * 20 + (col + kx)] * s_wv[i * 9 + ky * 3 + kx];
    }
    atomicAdd(&sraw[((size_t)b * 3 + phase) * 256 + t], acc);
  }
}

// dec merged: units 0..63 = dec(Midp)+loss vs cf; units 64..95 = dec(Recp)->rec2+minmax
// R16: D=3 counted-vmcnt(6) pipeline, 72KB LDS, 2 blocks/CU.
__global__ __launch_bounds__(256, 2) void conv_dec_k(
    const unsigned short* __restrict__ Midp, const unsigned short* __restrict__ Recp,
    const unsigned short* __restrict__ Wr, const float* __restrict__ bias,
    const float* __restrict__ cfref, float* __restrict__ rec2,
    float* __restrict__ lacc, unsigned* __restrict__ mm) {
  __shared__ __align__(16) char S[3][24576];
  const int t = threadIdx.x, lane = t & 63, wave = t >> 6;
  const int L = blockIdx.x;
  const int xcd = L & 7, sl = L >> 3;          // sl 0..95
  const int u12 = sl % 12, tile = sl / 12;     // tile 0..7
  const bool isLoss = u12 < 8;
  const int unit = isLoss ? (xcd * 8 + u12) : (64 + xcd * 4 + (u12 - 8));
  const int pt = tile & 3, ot = tile >> 2;

  int laneA[2], laneB[4];
#pragma unroll
  for (int r = 0; r < 2; ++r) {
    int id = r * 256 + t;
    int row = id >> 3, sub = id & 7, q = sub ^ (row & 7);
    int p = pt * 64 + row, y = p >> 4, x = p & 15;
    laneA[r] = (y * 18 + x) * 512 + q * 16;
  }
#pragma unroll
  for (int r = 0; r < 4; ++r) {
    int id = r * 256 + t;
    int row = id >> 3, sub = id & 7, q = sub ^ (row & 7);
    laneB[r] = (ot * 128 + row) * 4608 + q * 16;
  }
  const char* Ag = isLoss ? (const char*)Midp + (size_t)unit * 165888
                          : (const char*)Recp + (size_t)(unit - 64) * 165888;
  const char* Bg = (const char*)Wr;

  const int mlane = lane & 15, quad = lane >> 4;
  const int mw = wave >> 1, nw = wave & 1;
  int aoff[2][2], boff[4][2];
#pragma unroll
  for (int ks = 0; ks < 2; ++ks) {
#pragma unroll
    for (int i = 0; i < 2; ++i) {
      int rowm = mw * 32 + i * 16 + mlane;
      aoff[i][ks] = rowm * 128 + (((ks * 4 + quad) ^ (rowm & 7)) * 16);
    }
#pragma unroll
    for (int n = 0; n < 4; ++n) {
      int rown = nw * 64 + n * 16 + mlane;
      boff[n][ks] = 8192 + rown * 128 + (((ks * 4 + quad) ^ (rown & 7)) * 16);
    }
  }

  auto stage = [&](int kit, int buf) {         // 6 loads/thread
    int s = kit >> 2;
    int dy = s / 3, dx = s - dy * 3;
    int aG = (dy * 18 + dx) * 512 + (kit & 3) * 128;
    int bG = kit * 128;
    char* dst = S[buf];
#pragma unroll
    for (int r = 0; r < 2; ++r)
      gload_lds16(Ag + laneA[r] + aG, dst + r * 4096 + wave * 1024);
#pragma unroll
    for (int r = 0; r < 4; ++r)
      gload_lds16(Bg + laneB[r] + bG, dst + 8192 + r * 4096 + wave * 1024);
  };

  f32x4 acc[2][4] = {};
  auto compute = [&](int buf) {
    const char* Sb = S[buf];
#pragma unroll
    for (int ks = 0; ks < 2; ++ks) {
      short8 af[2], bf[4];
#pragma unroll
      for (int i = 0; i < 2; ++i) af[i] = *(const short8*)(Sb + aoff[i][ks]);
#pragma unroll
      for (int n = 0; n < 4; ++n) bf[n] = *(const short8*)(Sb + boff[n][ks]);
#pragma unroll
      for (int i = 0; i < 2; ++i)
#pragma unroll
        for (int n = 0; n < 4; ++n)
          acc[i][n] = __builtin_amdgcn_mfma_f32_16x16x32_bf16(af[i], bf[n], acc[i][n], 0, 0, 0);
    }
  };

  // D=3 pipeline: at each wait, stages kit (6 loads) + kit+1 (6) are in
  // flight; vmcnt(6) retires stage kit, leaving kit+1 flying across
  // compute(kit). Tail peeled with vmcnt(0).
  stage(0, 0);
  stage(1, 1);
#pragma unroll 3
  for (int kit = 0; kit < 35; ++kit) {
    asm volatile("s_waitcnt vmcnt(6)" ::: "memory");
    asm volatile("s_barrier" ::: "memory");
    int nb = kit + 2;
    if (nb < 36) stage(nb, nb % 3);
    compute(kit % 3);
  }
  asm volatile("s_waitcnt vmcnt(0)" ::: "memory");
  asm volatile("s_barrier" ::: "memory");
  compute(35 % 3);

  if (isLoss) {
    float ls = 0.f;
#pragma unroll
    for (int i = 0; i < 2; ++i) {
      int m0 = pt * 64 + mw * 32 + i * 16 + quad * 4;
#pragma unroll
      for (int n = 0; n < 4; ++n) {
        int oc = ot * 128 + nw * 64 + n * 16 + mlane;
        float bv = bias[oc];
        float4 c4 = *(const float4*)(cfref + (size_t)unit * 65536 + (size_t)oc * 256 + m0);
        float d0 = acc[i][n][0] + bv - c4.x;
        float d1 = acc[i][n][1] + bv - c4.y;
        float d2 = acc[i][n][2] + bv - c4.z;
        float d3 = acc[i][n][3] + bv - c4.w;
        ls += d0 * d0 + d1 * d1 + d2 * d2 + d3 * d3;
      }
    }
#pragma unroll
    for (int off = 32; off; off >>= 1) ls += __shfl_down(ls, off);
    __shared__ float sred[4];
    if (lane == 0) sred[wave] = ls;
    __syncthreads();
    if (t == 0) {
      float s = sred[0] + sred[1] + sred[2] + sred[3];
      atomicAdd(lacc, s);
    }
  } else {
    const int img2 = unit - 64;
    float mn = INFINITY, mx = -INFINITY;
#pragma unroll
    for (int i = 0; i < 2; ++i) {
      int m0 = pt * 64 + mw * 32 + i * 16 + quad * 4;
#pragma unroll
      for (int n = 0; n < 4; ++n) {
        int oc = ot * 128 + nw * 64 + n * 16 + mlane;
        float bv = bias[oc];
        float4 v;
        v.x = acc[i][n][0] + bv; v.y = acc[i][n][1] + bv;
        v.z = acc[i][n][2] + bv; v.w = acc[i][n][3] + bv;
        mn = fminf(mn, fminf(fminf(v.x, v.y), fminf(v.z, v.w)));
        mx = fmaxf(mx, fmaxf(fmaxf(v.x, v.y), fmaxf(v.z, v.w)));
        *(float4*)(rec2 + (size_t)img2 * 65536 + (size_t)oc * 256 + m0) = v;
      }
    }
#pragma unroll
    for (int off = 32; off; off >>= 1) {
      mn = fminf(mn, __shfl_down(mn, off));
      mx = fmaxf(mx, __shfl_down(mx, off));
    }
    __shared__ float smn[4], smx[4];
    if (lane == 0) { smn[wave] = mn; smx[wave] = mx; }
    __syncthreads();
    if (t == 0) {
      float a = fminf(fminf(smn[0], smn[1]), fminf(smn[2], smn[3]));
      float b2 = fmaxf(fmaxf(smx[0], smx[1]), fmaxf(smx[2], smx[3]));
      atomicMin(&mm[0], mapf(a));
      atomicMax(&mm[1], mapf(b2));
    }
  }
}

// score phase 0 only (rec path, needs mm + rec2), ic-split 8-way, atomicAdd into sraw
__global__ __launch_bounds__(256) void score_conv_k(
    const float* __restrict__ rec2, const float* __restrict__ wval,
    const unsigned* __restrict__ mm, float* __restrict__ sraw) {
  const int b = blockIdx.x, icc = blockIdx.z;
  const int t = threadIdx.x;
  const int row = t >> 4, col = t & 15;
  __shared__ float s_in[8 * 360];
  __shared__ float s_wv[72];
  for (int i = t; i < 8 * 360; i += 256) s_in[i] = 0.f;
  const float* src = rec2 + (size_t)b * 65536;
  float mn = unmapf(mm[0]), mx = unmapf(mm[1]);
  float sc = 2.f / (mx - mn);
  float sh = -mn * sc - 1.f;
  float acc = 0.f;
  for (int ic0 = icc * 32; ic0 < icc * 32 + 32; ic0 += 8) {
    __syncthreads();
#pragma unroll
    for (int i = 0; i < 8; ++i) {
      float v = fmaf(src[(ic0 + i) * 256 + t], sc, sh);
      s_in[i * 360 + (row + 1) * 20 + (col + 1)] = v;
    }
    if (t < 72) s_wv[t] = wval[ic0 * 9 + t];
    __syncthreads();
#pragma unroll
    for (int i = 0; i < 8; ++i)
#pragma unroll
      for (int ky = 0; ky < 3; ++ky)
#pragma unroll
        for (int kx = 0; kx < 3; ++kx)
          acc += s_in[i * 360 + (row + ky) * 20 + (col + kx)] * s_wv[i * 9 + ky * 3 + kx];
  }
  atomicAdd(&sraw[(size_t)b * 768 + t], acc);
}

// fused output, 4 elems/thread (float4)
__global__ __launch_bounds__(256) void fuse_k(
    const float* __restrict__ cf, const float* __restrict__ rec2,
    const float* __restrict__ sraw, const float* __restrict__ bval,
    const unsigned* __restrict__ mm, const float* __restrict__ lacc,
    float* __restrict__ outp) {
  const int e0 = (blockIdx.x * 256 + threadIdx.x) * 4;
  const int b = e0 >> 16;
  const int rest = e0 & 65535;
  const int pos = e0 & 255;
  const float mn = unmapf(mm[0]), mx = unmapf(mm[1]);
  const float sc = 2.f / (mx - mn), sh = -mn * sc - 1.f;
  const float4 srec = *(const float4*)&sraw[(size_t)b * 768 + pos];
  const float4 scA  = *(const float4*)&sraw[(size_t)b * 768 + 256 + pos];
  const float4 scB  = *(const float4*)&sraw[(size_t)b * 768 + 512 + pos];
  const float bv = bval[0];
  const float4 r4 = *(const float4*)&rec2[e0];
  const float4 f0 = *(const float4*)&cf[(size_t)b * 131072 + rest];
  const float4 f1 = *(const float4*)&cf[(size_t)b * 131072 + 65536 + rest];
  float4 o;
#pragma unroll
  for (int k = 0; k < 4; ++k) {
    float sr = ((const float*)&srec)[k];
    float a0 = ((const float*)&scA)[k];
    float a1 = ((const float*)&scB)[k];
    float z0 = fmaxf(sr + a0 + bv, 0.f);
    float z1 = fmaxf(sr + a1 + bv, 0.f);
    float s0 = 1.f / (1.f + expf(-z0));
    float s1 = 1.f / (1.f + expf(-z1));
    float w0 = 1.f / (1.f + expf(s1 - s0));
    float w1 = 1.f - w0;
    float rn = fmaf(((const float*)&r4)[k], sc, sh);
    float g0 = ((const float*)&f0)[k];
    float g1 = ((const float*)&f1)[k];
    ((float*)&o)[k] = 0.2f * (w0 * g0 + w1 * g1) + 0.8f * rn;
  }
  *(float4*)&outp[e0] = o;
  if (e0 == 0) outp[2097152] = lacc[0] * (1.f / 4194304.f);
}

extern "C" void kernel_launch(void* const* d_in, const int* in_sizes, int n_in,
                              void* d_out, int out_size, void* d_ws, size_t ws_size,
                              hipStream_t stream) {
  const float* cf    = (const float*)d_in[0];
  const float* fs    = (const float*)d_in[1];
  const float* fv    = (const float*)d_in[2];
  const float* fd    = (const float*)d_in[3];
  const float* w_enc = (const float*)d_in[4];
  const float* b_enc = (const float*)d_in[5];
  const float* w_dec = (const float*)d_in[6];
  const float* b_dec = (const float*)d_in[7];
  const float* w_val = (const float*)d_in[8];
  const float* b_val = (const float*)d_in[9];
  float* out = (float*)d_out;
  float* wsf = (float*)d_ws;

  // ws layout (float offsets):
  unsigned short* Xp   = (unsigned short*)wsf;                  // 64 img padded NHWC
  unsigned short* Midp = (unsigned short*)(wsf + 2654208);      // 64 img
  unsigned short* Recp = (unsigned short*)(wsf + 5308416);      // 32 img
  float* rec2 = wsf + 6635520;                                  // 2,097,152 NCHW f32
  unsigned short* WrE = (unsigned short*)(wsf + 8732672);
  unsigned short* WrD = (unsigned short*)(wsf + 9027584);
  unsigned short* Ans = (unsigned short*)(wsf + 9322496);
  unsigned short* BmT = (unsigned short*)(wsf + 10371072);
  float* sraw = wsf + 11419648;                                 // 24,576
  float* vd   = wsf + 11444224;                                 // 8,192
  int*   smr  = (int*)(wsf + 11452416);                         // 8,192
  float* lacc = wsf + 11460608;
  unsigned* mm = (unsigned*)(wsf + 11460609);

  prep_k<<<2809, 256, 0, stream>>>(cf, w_enc, w_dec, fv, Xp, WrE, WrD, smr, vd,
                                   (float4*)sraw, lacc, mm);
  ansbmt_k<<<2080, 256, 0, stream>>>(fs, fd, smr, vd, Ans, BmT, Recp);
  encrec_k<<<1536, 256, 0, stream>>>(Xp, WrE, b_enc, Midp, BmT, Ans, Recp,
                                     cf, w_val, sraw);
  conv_dec_k<<<768, 256, 0, stream>>>(Midp, Recp, WrD, b_dec, cf, rec2, lacc, mm);
  score_conv_k<<<dim3(32, 1, 8), 256, 0, stream>>>(rec2, w_val, mm, sraw);
  fuse_k<<<2048, 256, 0, stream>>>(cf, rec2, sraw, b_val, mm, lacc, out);
}

// Round 10
// 208.300 us; speedup vs baseline: 1.0753x; 1.0753x over previous
//
#include <hip/hip_runtime.h>
#include <math.h>

// Shapes (fixed): B=32, M=2, C=256, H=W=16, N=256, DIM=256, THR=0.1, RATIO=0.8
// out: fused (32,256,16,16) = 2,097,152 floats, then auto_enc_loss (1 float)
//
// R17 = R15 (212.8us, passing) with conv_dec reverted to the R7-measured
// 128px x 128oc 512-thread D=2 kernel (48.0us, best dec ever measured;
// 33% less L2->LDS staging traffic than the 64x128 tile: 442MB vs 664MB).
// Everything else identical to R15. 6 launches.

typedef __attribute__((ext_vector_type(8))) short short8;
typedef __attribute__((ext_vector_type(4))) float f32x4;

__device__ __forceinline__ void gload_lds16(const void* g, void* l) {
  __builtin_amdgcn_global_load_lds(
      (const __attribute__((address_space(1))) void*)g,
      (__attribute__((address_space(3))) void*)l, 16, 0, 0);
}

__device__ __forceinline__ unsigned short f2bf(float f) {
  unsigned u = __float_as_uint(f);
  unsigned r = (u + 0x7FFFu + ((u >> 16) & 1u)) >> 16;  // RNE
  return (unsigned short)r;
}

__device__ __forceinline__ unsigned mapf(float f) {
  unsigned u = __float_as_uint(f);
  return (u & 0x80000000u) ? ~u : (u | 0x80000000u);   // monotone float->uint
}
__device__ __forceinline__ float unmapf(unsigned u) {
  unsigned v = (u & 0x80000000u) ? (u & 0x7fffffffu) : ~u;
  return __uint_as_float(v);
}

// ---------------- merged prep: pack | weight-repack | halo-zero | slots | init
__global__ __launch_bounds__(256) void prep_k(
    const float* __restrict__ cf, const float* __restrict__ we,
    const float* __restrict__ wd, const float* __restrict__ fv,
    unsigned short* __restrict__ Xp, unsigned short* __restrict__ WrE,
    unsigned short* __restrict__ WrD, int* __restrict__ smr,
    float* __restrict__ vd, float4* __restrict__ sraw4,
    float* __restrict__ lacc, unsigned* __restrict__ mm) {
  const int bx = blockIdx.x, t = threadIdx.x;
  if (bx < 2048) {                       // pack: cf NCHW f32 -> padded NHWC bf16
    int xcdP = bx >> 8, r = bx & 255;    // XCD-grouped (matches enc img map)
    int img = xcdP * 8 + (r >> 5), ch = r & 31;
    int p = t;
    int ic0 = ch * 8;
    const float* sp = cf + (size_t)img * 65536 + (size_t)ic0 * 256 + p;
    unsigned short h[8];
#pragma unroll
    for (int i = 0; i < 8; ++i) h[i] = f2bf(sp[i * 256]);
    int y = p >> 4, x = p & 15;
    uint4 u;
    u.x = h[0] | (h[1] << 16); u.y = h[2] | (h[3] << 16);
    u.z = h[4] | (h[5] << 16); u.w = h[6] | (h[7] << 16);
    *(uint4*)&Xp[(size_t)img * 82944 + (size_t)(y * 18 + x + 19) * 256 + ic0] = u;
  } else if (bx < 2624) {                // wrk: OIHW f32 -> Wr[oc][s][ic] bf16
    int idx = (bx - 2048) * 256 + t;
    int ch = idx & 31, rest = idx >> 5;
    int s = rest % 9, ocx = rest / 9;
    int oc = ocx & 255, cv = ocx >> 8;
    const float* w = cv ? wd : we;
    unsigned short* o = cv ? WrD : WrE;
    int ic0 = ch * 8;
    unsigned short h[8];
#pragma unroll
    for (int i = 0; i < 8; ++i) h[i] = f2bf(w[(size_t)oc * 2304 + (ic0 + i) * 9 + s]);
    uint4 u;
    u.x = h[0] | (h[1] << 16); u.y = h[2] | (h[3] << 16);
    u.z = h[4] | (h[5] << 16); u.w = h[6] | (h[7] << 16);
    *(uint4*)&o[(size_t)oc * 2304 + s * 256 + ic0] = u;
  } else if (bx < 2752) {                // halo zero: Xp imgs 0..63, Midp 64..127
    int img = bx - 2624;
    uint4* base = (uint4*)Xp + (size_t)img * 10368;
    uint4 z; z.x = z.y = z.z = z.w = 0;
    for (int it = t; it < 2176; it += 256) {
      int px = it >> 5, c = it & 31;
      int y, x;
      if (px < 18)      { y = 0;  x = px; }
      else if (px < 36) { y = 17; x = px - 18; }
      else if (px < 52) { y = px - 35; x = 0; }
      else              { y = px - 51; x = 17; }
      base[(y * 18 + x) * 32 + c] = z;
    }
  } else if (bx < 2784) {                // slots: rank budget + dest maps
    const int b = bx - 2752;
    const float v0 = fv[(size_t)b * 512 + t];
    const float v1 = fv[(size_t)b * 512 + 256 + t];
    const unsigned long long bal0 = __ballot(v0 > 0.1f);
    const unsigned long long bal1 = __ballot(v1 > 0.1f);
    __shared__ int cnt0[4], cnt1[4], fc[2];
    const int wid = t >> 6, lane = t & 63;
    if (lane == 0) { cnt0[wid] = __popcll(bal0); cnt1[wid] = __popcll(bal1); }
    smr[b * 256 + t] = -1;
    vd[b * 256 + t] = 0.f;
    __syncthreads();
    if (t == 0) {
      int c0 = cnt0[0] + cnt0[1] + cnt0[2] + cnt0[3];
      int c1 = cnt1[0] + cnt1[1] + cnt1[2] + cnt1[3];
      int total = c0 + c1;
      int f0, f1;
      if (total > 256) {
        int a0 = (int)rintf(256.0f * (float)c0 / (float)total);
        f0 = a0; f1 = 256 - a0;
      } else { f0 = c0; f1 = c1; }
      fc[0] = max(f0, 0); fc[1] = max(f1, 0);
    }
    __syncthreads();
    const int c0 = fc[0], c1 = fc[1];
    if (t < c0) { smr[b * 256 + t] = t; vd[b * 256 + t] = v0; }
    if (t < c1) {
      int d = c0 + t;
      if (d < 256) { smr[b * 256 + d] = 256 + t; vd[b * 256 + d] = v1; }
    }
  } else {                               // zero sraw (24 blocks) + init (1)
    int z = bx - 2784;
    if (z < 24) {
      float4 zz; zz.x = zz.y = zz.z = zz.w = 0.f;
      sraw4[z * 256 + t] = zz;
    } else if (t == 0) {
      lacc[0] = 0.f; mm[0] = 0xFFFFFFFFu; mm[1] = 0u;
    }
  }
}

// ---------------- merged: ansb [0,1024) | bmt 1-jg-per-block [1024,2048) | Recp halo [2048,2080)
__global__ __launch_bounds__(256) void ansbmt_k(
    const float* __restrict__ fs, const float* __restrict__ fd,
    const int* __restrict__ smr, const float* __restrict__ vd,
    unsigned short* __restrict__ Ans, unsigned short* __restrict__ BmT,
    unsigned short* __restrict__ Recp) {
  const int bx = blockIdx.x, t = threadIdx.x;
  if (bx < 1024) {                       // Ans[b][c][j] = ns[c][j]*v_j
    int idx = bx * 256 + t;
    int ch = idx & 31, c = (idx >> 5) & 255, b = idx >> 13;
    int j0 = ch * 8;
    int si = smr[b * 256 + c];
    unsigned short h[8] = {0, 0, 0, 0, 0, 0, 0, 0};
    if (si >= 0) {
      int m = si >> 8, r = si & 255;
      const float* fp = fs + (((size_t)b * 2 + m) * 256 + r) * 256 + j0;
      const float* vp = vd + b * 256 + j0;
#pragma unroll
      for (int i = 0; i < 8; ++i) h[i] = f2bf(fp[i] * vp[i]);
    }
    uint4 u;
    u.x = h[0] | (h[1] << 16); u.y = h[2] | (h[3] << 16);
    u.z = h[4] | (h[5] << 16); u.w = h[6] | (h[7] << 16);
    *(uint4*)&Ans[(size_t)b * 65536 + c * 256 + j0] = u;
  } else if (bx < 2048) {                // BmT[b][p][jg*8..+8] = fd[b,m_p,jg*8+i,r_p]
    __shared__ float sIn[4096];          // 8 j x 2 m x 256 r
    const int q0 = bx - 1024;
    const int b = q0 >> 5, jg = q0 & 31;  // 32 b x 32 jg, fully parallel
    const int sp = smr[b * 256 + t];
    const int m_p = sp >> 8, r_p = sp & 255;
#pragma unroll
    for (int u = 0; u < 4; ++u) {
      int q = t * 4 + u;
      int rr = q >> 6, w = q & 63;
      int m = rr >> 3, i = rr & 7;
      float4 f = ((const float4*)fd)[((size_t)(b * 2 + m) * 256 + jg * 8 + i) * 64 + w];
      *(float4*)&sIn[i * 512 + m * 256 + w * 4] = f;
    }
    __syncthreads();
    unsigned short h[8] = {0, 0, 0, 0, 0, 0, 0, 0};
    if (sp >= 0) {
#pragma unroll
      for (int i = 0; i < 8; ++i) h[i] = f2bf(sIn[i * 512 + m_p * 256 + r_p]);
    }
    uint4 u;
    u.x = h[0] | (h[1] << 16); u.y = h[2] | (h[3] << 16);
    u.z = h[4] | (h[5] << 16); u.w = h[6] | (h[7] << 16);
    *(uint4*)&BmT[(size_t)b * 65536 + t * 256 + jg * 8] = u;
  } else {                               // Recp halo zero (32 imgs)
    int img = bx - 2048;
    uint4* base = (uint4*)Recp + (size_t)img * 10368;
    uint4 z; z.x = z.y = z.z = z.w = 0;
    for (int it = t; it < 2176; it += 256) {
      int px = it >> 5, c = it & 31;
      int y, x;
      if (px < 18)      { y = 0;  x = px; }
      else if (px < 36) { y = 17; x = px - 18; }
      else if (px < 52) { y = px - 35; x = 0; }
      else              { y = px - 51; x = 17; }
      base[(y * 18 + x) * 32 + c] = z;
    }
  }
}

// ---------------- merged conv_enc [0,512) + recgemm [512,1024) + score-cf [1024,1536)
__global__ __launch_bounds__(256, 3) void encrec_k(
    const unsigned short* __restrict__ Xin, const unsigned short* __restrict__ Wr,
    const float* __restrict__ bias,          unsigned short* __restrict__ outp,
    const unsigned short* __restrict__ BmT,  const unsigned short* __restrict__ Ans,
    unsigned short* __restrict__ Recp,       const float* __restrict__ cf,
    const float* __restrict__ wval,          float* __restrict__ sraw) {
  __shared__ __align__(16) char SS[49152];
  const int t = threadIdx.x, lane = t & 63, wave = t >> 6;
  const int L = blockIdx.x;

  if (L < 512) {  // ================= enc =================
    char (*S)[24576] = (char(*)[24576])SS;
    const int xcd = L & 7, sl = L >> 3;          // sl 0..63
    const int img = xcd * 8 + (sl & 7);
    const int tile = sl >> 3;                    // 0..7
    const int pt = tile & 3, ot = tile >> 2;

    int laneA[2], laneB[4];
#pragma unroll
    for (int r = 0; r < 2; ++r) {
      int id = r * 256 + t;
      int row = id >> 3, sub = id & 7, q = sub ^ (row & 7);
      int p = pt * 64 + row, y = p >> 4, x = p & 15;
      laneA[r] = (y * 18 + x) * 512 + q * 16;
    }
#pragma unroll
    for (int r = 0; r < 4; ++r) {
      int id = r * 256 + t;
      int row = id >> 3, sub = id & 7, q = sub ^ (row & 7);
      laneB[r] = (ot * 128 + row) * 4608 + q * 16;
    }
    const char* Ag = (const char*)Xin + (size_t)img * 165888;
    const char* Bg = (const char*)Wr;

    const int mlane = lane & 15, quad = lane >> 4;
    const int mw = wave >> 1, nw = wave & 1;
    int aoff[2][2], boff[4][2];
#pragma unroll
    for (int ks = 0; ks < 2; ++ks) {
#pragma unroll
      for (int i = 0; i < 2; ++i) {
        int rowm = mw * 32 + i * 16 + mlane;
        aoff[i][ks] = rowm * 128 + (((ks * 4 + quad) ^ (rowm & 7)) * 16);
      }
#pragma unroll
      for (int n = 0; n < 4; ++n) {
        int rown = nw * 64 + n * 16 + mlane;
        boff[n][ks] = 8192 + rown * 128 + (((ks * 4 + quad) ^ (rown & 7)) * 16);
      }
    }

    auto stage = [&](int kit, int buf) {         // 6 loads/thread
      int s = kit >> 2;
      int dy = s / 3, dx = s - dy * 3;
      int aG = (dy * 18 + dx) * 512 + (kit & 3) * 128;
      int bG = kit * 128;
      char* dst = S[buf];
#pragma unroll
      for (int r = 0; r < 2; ++r)
        gload_lds16(Ag + laneA[r] + aG, dst + r * 4096 + wave * 1024);
#pragma unroll
      for (int r = 0; r < 4; ++r)
        gload_lds16(Bg + laneB[r] + bG, dst + 8192 + r * 4096 + wave * 1024);
    };

    f32x4 acc[2][4] = {};
    auto compute = [&](int buf) {
      const char* Sb = S[buf];
#pragma unroll
      for (int ks = 0; ks < 2; ++ks) {
        short8 af[2], bf[4];
#pragma unroll
        for (int i = 0; i < 2; ++i) af[i] = *(const short8*)(Sb + aoff[i][ks]);
#pragma unroll
        for (int n = 0; n < 4; ++n) bf[n] = *(const short8*)(Sb + boff[n][ks]);
#pragma unroll
        for (int i = 0; i < 2; ++i)
#pragma unroll
          for (int n = 0; n < 4; ++n)
            acc[i][n] = __builtin_amdgcn_mfma_f32_16x16x32_bf16(af[i], bf[n], acc[i][n], 0, 0, 0);
      }
    };

    stage(0, 0);
    for (int kit = 0; kit < 36; ++kit) {
      int cur = kit & 1;
      asm volatile("s_waitcnt vmcnt(0)" ::: "memory");
      asm volatile("s_barrier" ::: "memory");
      if (kit + 1 < 36) stage(kit + 1, 1 - cur);
      compute(cur);
    }

#pragma unroll
    for (int i = 0; i < 2; ++i) {
      int m0 = pt * 64 + mw * 32 + i * 16 + quad * 4;
#pragma unroll
      for (int n = 0; n < 4; ++n) {
        int oc = ot * 128 + nw * 64 + n * 16 + mlane;
        float bv = bias[oc];
#pragma unroll
        for (int r = 0; r < 4; ++r) {
          int p = m0 + r;
          int y = p >> 4, x = p & 15;
          float v = fmaxf(acc[i][n][r] + bv, 0.f);
          outp[(size_t)img * 82944 + (size_t)(y * 18 + x + 19) * 256 + oc] = f2bf(v);
        }
      }
    }
  } else if (L < 1024) {  // ================= recgemm =================
    unsigned short (*S)[8192] = (unsigned short(*)[8192])SS;
    const int L2 = L - 512;
    const int b = L2 >> 4, tile = L2 & 15;
    const int pt = tile >> 2, ct = tile & 3;

    int laneA[2], laneB[2];
#pragma unroll
    for (int j = 0; j < 2; ++j) {
      int id = (wave * 2 + j) * 64 + lane;
      int row = id >> 3, q = (id & 7) ^ (row & 7);
      laneA[j] = (pt * 64 + row) * 512 + q * 16;
      laneB[j] = (ct * 64 + row) * 512 + q * 16;
    }
    const char* Ag = (const char*)BmT + (size_t)b * 131072;
    const char* Bg = (const char*)Ans + (size_t)b * 131072;

    const int mlane = lane & 15, quad = lane >> 4;
    const int mw = wave >> 1, nw = wave & 1;
    int aoff[2][2], boff[2][2];
#pragma unroll
    for (int ks = 0; ks < 2; ++ks) {
#pragma unroll
      for (int i = 0; i < 2; ++i) {
        int rowm = mw * 32 + i * 16 + mlane;
        aoff[i][ks] = rowm * 128 + (((ks * 4 + quad) ^ (rowm & 7)) * 16);
        int rown = nw * 32 + i * 16 + mlane;
        boff[i][ks] = 8192 + rown * 128 + (((ks * 4 + quad) ^ (rown & 7)) * 16);
      }
    }

    auto stage = [&](int kit, int buf) {
      int g = kit * 128;
      char* dst = (char*)S[buf];
#pragma unroll
      for (int j = 0; j < 2; ++j)
        gload_lds16(Ag + laneA[j] + g, dst + (wave * 2 + j) * 1024);
#pragma unroll
      for (int j = 0; j < 2; ++j)
        gload_lds16(Bg + laneB[j] + g, dst + 8192 + (wave * 2 + j) * 1024);
    };

    f32x4 acc[2][2] = {};
    auto compute = [&](int buf) {
      const char* Sb = (const char*)S[buf];
#pragma unroll
      for (int ks = 0; ks < 2; ++ks) {
        short8 af[2], bf[2];
#pragma unroll
        for (int i = 0; i < 2; ++i) {
          af[i] = *(const short8*)(Sb + aoff[i][ks]);
          bf[i] = *(const short8*)(Sb + boff[i][ks]);
        }
#pragma unroll
        for (int i = 0; i < 2; ++i)
#pragma unroll
          for (int n = 0; n < 2; ++n)
            acc[i][n] = __builtin_amdgcn_mfma_f32_16x16x32_bf16(af[i], bf[n], acc[i][n], 0, 0, 0);
      }
    };

    stage(0, 0);
    stage(1, 1);
    for (int kit = 0; kit < 3; ++kit) {
      asm volatile("s_waitcnt vmcnt(4)" ::: "memory");
      asm volatile("s_barrier" ::: "memory");
      int nb = kit + 2;
      if (nb < 4) stage(nb, nb % 3);
      compute(kit % 3);
    }
    asm volatile("s_waitcnt vmcnt(0)" ::: "memory");
    asm volatile("s_barrier" ::: "memory");
    compute(3 % 3);

#pragma unroll
    for (int i = 0; i < 2; ++i) {
      int m0 = pt * 64 + mw * 32 + i * 16 + quad * 4;
#pragma unroll
      for (int n = 0; n < 2; ++n) {
        int cc = ct * 64 + nw * 32 + n * 16 + mlane;
#pragma unroll
        for (int r = 0; r < 4; ++r) {
          int p = m0 + r;
          int y = p >> 4, x = p & 15;
          Recp[(size_t)b * 82944 + (size_t)(y * 18 + x + 19) * 256 + cc] = f2bf(acc[i][n][r]);
        }
      }
    }
  } else {  // ============ score phases 1,2 (cf-only, no dec dependency) ============
    const int u = L - 1024;              // 0..511
    const int b = u & 31, phase = 1 + ((u >> 5) & 1), icc = u >> 6;
    const int row = t >> 4, col = t & 15;
    float* s_in = (float*)SS;            // 11520 B
    float* s_wv = (float*)(SS + 11776);  // 288 B
    for (int i = t; i < 8 * 360; i += 256) s_in[i] = 0.f;
    const float* srcf = cf + ((size_t)b * 2 + (phase - 1)) * 65536;
    const int wofs = 2304;
    float acc = 0.f;
    for (int ic0 = icc * 32; ic0 < icc * 32 + 32; ic0 += 8) {
      __syncthreads();
#pragma unroll
      for (int i = 0; i < 8; ++i)
        s_in[i * 360 + (row + 1) * 20 + (col + 1)] = srcf[(ic0 + i) * 256 + t];
      if (t < 72) s_wv[t] = wval[wofs + ic0 * 9 + t];
      __syncthreads();
#pragma unroll
      for (int i = 0; i < 8; ++i)
#pragma unroll
        for (int ky = 0; ky < 3; ++ky)
#pragma unroll
          for (int kx = 0; kx < 3; ++kx)
            acc += s_in[i * 360 + (row + ky) * 20 + (col + kx)] * s_wv[i * 9 + ky * 3 + kx];
    }
    atomicAdd(&sraw[((size_t)b * 3 + phase) * 256 + t], acc);
  }
}

// dec merged (R7 version): 128px x 128oc, 512 threads, D=2 vmcnt(0), 64KB LDS.
// units 0..63 = dec(Midp)+loss vs cf; units 64..95 = dec(Recp)->rec2+minmax
__global__ __launch_bounds__(512, 4) void conv_dec_k(
    const unsigned short* __restrict__ Midp, const unsigned short* __restrict__ Recp,
    const unsigned short* __restrict__ Wr, const float* __restrict__ bias,
    const float* __restrict__ cfref, float* __restrict__ rec2,
    float* __restrict__ lacc, unsigned* __restrict__ mm) {
  __shared__ __align__(16) char S[2][32768];
  const int t = threadIdx.x, lane = t & 63, wave = t >> 6;
  const int L = blockIdx.x;
  const int xcd = L & 7, sl = L >> 3;          // 384 blocks: sl 0..47
  const int u12 = sl % 12, tile = sl / 12;     // tile 0..3
  const int unit = xcd * 12 + u12;             // 0..95
  const bool isLoss = unit < 64;
  const int pt = tile >> 1, ot = tile & 1;

  int laneA[2], laneB[2];
#pragma unroll
  for (int r = 0; r < 2; ++r) {
    int id = r * 512 + t;
    int row = id >> 3, sub = id & 7, q = sub ^ (row & 7);
    int p = pt * 128 + row, y = p >> 4, x = p & 15;
    laneA[r] = (y * 18 + x) * 512 + q * 16;
    laneB[r] = (ot * 128 + row) * 4608 + q * 16;
  }
  const char* Ag = isLoss ? (const char*)Midp + (size_t)unit * 165888
                          : (const char*)Recp + (size_t)(unit - 64) * 165888;
  const char* Bg = (const char*)Wr;

  const int mlane = lane & 15, quad = lane >> 4;
  const int mw = wave >> 1, nw = wave & 1;
  int aoff[2][2], boff[4][2];
#pragma unroll
  for (int ks = 0; ks < 2; ++ks) {
#pragma unroll
    for (int i = 0; i < 2; ++i) {
      int rowm = mw * 32 + i * 16 + mlane;
      aoff[i][ks] = rowm * 128 + (((ks * 4 + quad) ^ (rowm & 7)) * 16);
    }
#pragma unroll
    for (int n = 0; n < 4; ++n) {
      int rown = nw * 64 + n * 16 + mlane;
      boff[n][ks] = 16384 + rown * 128 + (((ks * 4 + quad) ^ (rown & 7)) * 16);
    }
  }

  auto stage = [&](int kit, int buf) {
    int s = kit >> 2;
    int dy = s / 3, dx = s - dy * 3;
    int aG = (dy * 18 + dx) * 512 + (kit & 3) * 128;
    int bG = kit * 128;
    char* dst = S[buf];
#pragma unroll
    for (int r = 0; r < 2; ++r)
      gload_lds16(Ag + laneA[r] + aG, dst + r * 8192 + wave * 1024);
#pragma unroll
    for (int r = 0; r < 2; ++r)
      gload_lds16(Bg + laneB[r] + bG, dst + 16384 + r * 8192 + wave * 1024);
  };

  f32x4 acc[2][4] = {};
  auto compute = [&](int buf) {
    const char* Sb = S[buf];
#pragma unroll
    for (int ks = 0; ks < 2; ++ks) {
      short8 af[2], bf[4];
#pragma unroll
      for (int i = 0; i < 2; ++i) af[i] = *(const short8*)(Sb + aoff[i][ks]);
#pragma unroll
      for (int n = 0; n < 4; ++n) bf[n] = *(const short8*)(Sb + boff[n][ks]);
#pragma unroll
      for (int i = 0; i < 2; ++i)
#pragma unroll
        for (int n = 0; n < 4; ++n)
          acc[i][n] = __builtin_amdgcn_mfma_f32_16x16x32_bf16(af[i], bf[n], acc[i][n], 0, 0, 0);
    }
  };

  stage(0, 0);
  for (int kit = 0; kit < 36; ++kit) {
    int cur = kit & 1;
    asm volatile("s_waitcnt vmcnt(0)" ::: "memory");
    asm volatile("s_barrier" ::: "memory");
    if (kit + 1 < 36) stage(kit + 1, 1 - cur);
    compute(cur);
  }

  if (isLoss) {
    float ls = 0.f;
#pragma unroll
    for (int i = 0; i < 2; ++i) {
      int m0 = pt * 128 + mw * 32 + i * 16 + quad * 4;
#pragma unroll
      for (int n = 0; n < 4; ++n) {
        int oc = ot * 128 + nw * 64 + n * 16 + mlane;
        float bv = bias[oc];
        float4 c4 = *(const float4*)(cfref + (size_t)unit * 65536 + (size_t)oc * 256 + m0);
        float d0 = acc[i][n][0] + bv - c4.x;
        float d1 = acc[i][n][1] + bv - c4.y;
        float d2 = acc[i][n][2] + bv - c4.z;
        float d3 = acc[i][n][3] + bv - c4.w;
        ls += d0 * d0 + d1 * d1 + d2 * d2 + d3 * d3;
      }
    }
#pragma unroll
    for (int off = 32; off; off >>= 1) ls += __shfl_down(ls, off);
    __shared__ float sred[8];
    if (lane == 0) sred[wave] = ls;
    __syncthreads();
    if (t == 0) {
      float s = 0.f;
#pragma unroll
      for (int w = 0; w < 8; ++w) s += sred[w];
      atomicAdd(lacc, s);
    }
  } else {
    const int img2 = unit - 64;
    float mn = INFINITY, mx = -INFINITY;
#pragma unroll
    for (int i = 0; i < 2; ++i) {
      int m0 = pt * 128 + mw * 32 + i * 16 + quad * 4;
#pragma unroll
      for (int n = 0; n < 4; ++n) {
        int oc = ot * 128 + nw * 64 + n * 16 + mlane;
        float bv = bias[oc];
        float4 v;
        v.x = acc[i][n][0] + bv; v.y = acc[i][n][1] + bv;
        v.z = acc[i][n][2] + bv; v.w = acc[i][n][3] + bv;
        mn = fminf(mn, fminf(fminf(v.x, v.y), fminf(v.z, v.w)));
        mx = fmaxf(mx, fmaxf(fmaxf(v.x, v.y), fmaxf(v.z, v.w)));
        *(float4*)(rec2 + (size_t)img2 * 65536 + (size_t)oc * 256 + m0) = v;
      }
    }
#pragma unroll
    for (int off = 32; off; off >>= 1) {
      mn = fminf(mn, __shfl_down(mn, off));
      mx = fmaxf(mx, __shfl_down(mx, off));
    }
    __shared__ float smn[8], smx[8];
    if (lane == 0) { smn[wave] = mn; smx[wave] = mx; }
    __syncthreads();
    if (t == 0) {
      float a = INFINITY, b2 = -INFINITY;
#pragma unroll
      for (int w = 0; w < 8; ++w) { a = fminf(a, smn[w]); b2 = fmaxf(b2, smx[w]); }
      atomicMin(&mm[0], mapf(a));
      atomicMax(&mm[1], mapf(b2));
    }
  }
}

// score phase 0 only (rec path, needs mm + rec2), ic-split 8-way, atomicAdd into sraw
__global__ __launch_bounds__(256) void score_conv_k(
    const float* __restrict__ rec2, const float* __restrict__ wval,
    const unsigned* __restrict__ mm, float* __restrict__ sraw) {
  const int b = blockIdx.x, icc = blockIdx.z;
  const int t = threadIdx.x;
  const int row = t >> 4, col = t & 15;
  __shared__ float s_in[8 * 360];
  __shared__ float s_wv[72];
  for (int i = t; i < 8 * 360; i += 256) s_in[i] = 0.f;
  const float* src = rec2 + (size_t)b * 65536;
  float mn = unmapf(mm[0]), mx = unmapf(mm[1]);
  float sc = 2.f / (mx - mn);
  float sh = -mn * sc - 1.f;
  float acc = 0.f;
  for (int ic0 = icc * 32; ic0 < icc * 32 + 32; ic0 += 8) {
    __syncthreads();
#pragma unroll
    for (int i = 0; i < 8; ++i) {
      float v = fmaf(src[(ic0 + i) * 256 + t], sc, sh);
      s_in[i * 360 + (row + 1) * 20 + (col + 1)] = v;
    }
    if (t < 72) s_wv[t] = wval[ic0 * 9 + t];
    __syncthreads();
#pragma unroll
    for (int i = 0; i < 8; ++i)
#pragma unroll
      for (int ky = 0; ky < 3; ++ky)
#pragma unroll
        for (int kx = 0; kx < 3; ++kx)
          acc += s_in[i * 360 + (row + ky) * 20 + (col + kx)] * s_wv[i * 9 + ky * 3 + kx];
  }
  atomicAdd(&sraw[(size_t)b * 768 + t], acc);
}

// fused output, 4 elems/thread (float4)
__global__ __launch_bounds__(256) void fuse_k(
    const float* __restrict__ cf, const float* __restrict__ rec2,
    const float* __restrict__ sraw, const float* __restrict__ bval,
    const unsigned* __restrict__ mm, const float* __restrict__ lacc,
    float* __restrict__ outp) {
  const int e0 = (blockIdx.x * 256 + threadIdx.x) * 4;
  const int b = e0 >> 16;
  const int rest = e0 & 65535;
  const int pos = e0 & 255;
  const float mn = unmapf(mm[0]), mx = unmapf(mm[1]);
  const float sc = 2.f / (mx - mn), sh = -mn * sc - 1.f;
  const float4 srec = *(const float4*)&sraw[(size_t)b * 768 + pos];
  const float4 scA  = *(const float4*)&sraw[(size_t)b * 768 + 256 + pos];
  const float4 scB  = *(const float4*)&sraw[(size_t)b * 768 + 512 + pos];
  const float bv = bval[0];
  const float4 r4 = *(const float4*)&rec2[e0];
  const float4 f0 = *(const float4*)&cf[(size_t)b * 131072 + rest];
  const float4 f1 = *(const float4*)&cf[(size_t)b * 131072 + 65536 + rest];
  float4 o;
#pragma unroll
  for (int k = 0; k < 4; ++k) {
    float sr = ((const float*)&srec)[k];
    float a0 = ((const float*)&scA)[k];
    float a1 = ((const float*)&scB)[k];
    float z0 = fmaxf(sr + a0 + bv, 0.f);
    float z1 = fmaxf(sr + a1 + bv, 0.f);
    float s0 = 1.f / (1.f + expf(-z0));
    float s1 = 1.f / (1.f + expf(-z1));
    float w0 = 1.f / (1.f + expf(s1 - s0));
    float w1 = 1.f - w0;
    float rn = fmaf(((const float*)&r4)[k], sc, sh);
    float g0 = ((const float*)&f0)[k];
    float g1 = ((const float*)&f1)[k];
    ((float*)&o)[k] = 0.2f * (w0 * g0 + w1 * g1) + 0.8f * rn;
  }
  *(float4*)&outp[e0] = o;
  if (e0 == 0) outp[2097152] = lacc[0] * (1.f / 4194304.f);
}

extern "C" void kernel_launch(void* const* d_in, const int* in_sizes, int n_in,
                              void* d_out, int out_size, void* d_ws, size_t ws_size,
                              hipStream_t stream) {
  const float* cf    = (const float*)d_in[0];
  const float* fs    = (const float*)d_in[1];
  const float* fv    = (const float*)d_in[2];
  const float* fd    = (const float*)d_in[3];
  const float* w_enc = (const float*)d_in[4];
  const float* b_enc = (const float*)d_in[5];
  const float* w_dec = (const float*)d_in[6];
  const float* b_dec = (const float*)d_in[7];
  const float* w_val = (const float*)d_in[8];
  const float* b_val = (const float*)d_in[9];
  float* out = (float*)d_out;
  float* wsf = (float*)d_ws;

  // ws layout (float offsets):
  unsigned short* Xp   = (unsigned short*)wsf;                  // 64 img padded NHWC
  unsigned short* Midp = (unsigned short*)(wsf + 2654208);      // 64 img
  unsigned short* Recp = (unsigned short*)(wsf + 5308416);      // 32 img
  float* rec2 = wsf + 6635520;                                  // 2,097,152 NCHW f32
  unsigned short* WrE = (unsigned short*)(wsf + 8732672);
  unsigned short* WrD = (unsigned short*)(wsf + 9027584);
  unsigned short* Ans = (unsigned short*)(wsf + 9322496);
  unsigned short* BmT = (unsigned short*)(wsf + 10371072);
  float* sraw = wsf + 11419648;                                 // 24,576
  float* vd   = wsf + 11444224;                                 // 8,192
  int*   smr  = (int*)(wsf + 11452416);                         // 8,192
  float* lacc = wsf + 11460608;
  unsigned* mm = (unsigned*)(wsf + 11460609);

  prep_k<<<2809, 256, 0, stream>>>(cf, w_enc, w_dec, fv, Xp, WrE, WrD, smr, vd,
                                   (float4*)sraw, lacc, mm);
  ansbmt_k<<<2080, 256, 0, stream>>>(fs, fd, smr, vd, Ans, BmT, Recp);
  encrec_k<<<1536, 256, 0, stream>>>(Xp, WrE, b_enc, Midp, BmT, Ans, Recp,
                                     cf, w_val, sraw);
  conv_dec_k<<<384, 512, 0, stream>>>(Midp, Recp, WrD, b_dec, cf, rec2, lacc, mm);
  score_conv_k<<<dim3(32, 1, 8), 256, 0, stream>>>(rec2, w_val, mm, sraw);
  fuse_k<<<2048, 256, 0, stream>>>(cf, rec2, sraw, b_val, mm, lacc, out);
}